// Round 3
// baseline (129.407 us; speedup 1.0000x reference)
//
#include <hip/hip_runtime.h>

#define PP 10
#define LL 6
#define NIMG 4
#define HW (1024*1024)
#define BINS 66          // 60 inter bins (l*10+p) + 6 label-count bins (60+l)
#define BX 128           // blocks per image
#define TPB 256
#define ITERS (HW / 4 / (BX * TPB))   // = 8, exact

// ws layout: partial[img][bx][b] = ws[(img*BX + bx)*BINS + b], written
// non-atomically by each block (no memset needed; every slot is overwritten).

__global__ __launch_bounds__(TPB) void accum_kernel(
    const float* __restrict__ pred,
    const int*   __restrict__ pconn,
    const int*   __restrict__ lconn,
    float*       __restrict__ ws)
{
    // Per-thread privatized bins: sb[bin*256 + tid]. Bank = tid % 32 ->
    // 2 lanes/bank for a wave64 access = conflict-free (m136).
    __shared__ float sb[BINS * TPB];

    const int tid = threadIdx.x;
    const int img = blockIdx.y;
    const size_t base = (size_t)img * HW;

    // zero LDS (float4 stores)
    {
        float4* sb4 = (float4*)sb;
        const int n4 = BINS * TPB / 4;   // 4224
        for (int i = tid; i < n4; i += TPB) sb4[i] = make_float4(0.f, 0.f, 0.f, 0.f);
    }
    __syncthreads();

    const float4* __restrict__ p4  = (const float4*)(pred  + base);
    const int4*   __restrict__ pc4 = (const int4*)(pconn + base);
    const int4*   __restrict__ lc4 = (const int4*)(lconn + base);

    const int v0 = blockIdx.x * TPB + tid;
    const int stride = BX * TPB;  // 32768 vec4s

    // Hoist ALL loads first: 24 outstanding 16B loads/wave -> latency hidden.
    float4 p[ITERS]; int4 pc[ITERS], lc[ITERS];
#pragma unroll
    for (int i = 0; i < ITERS; ++i) {
        const int v = v0 + i * stride;
        p[i]  = p4[v];
        pc[i] = pc4[v];
        lc[i] = lc4[v];
    }

    // Private accumulation via ds_add_f32 (atomicAdd with unused result):
    // 1 LDS instr per update instead of read+write pair. No cross-thread
    // sharing of a column, so this is just a cheap fused RMW.
#pragma unroll
    for (int i = 0; i < ITERS; ++i) {
        atomicAdd(&sb[(lc[i].x * PP + pc[i].x) * TPB + tid], p[i].x);
        atomicAdd(&sb[(60 + lc[i].x) * TPB + tid], 1.0f);
        atomicAdd(&sb[(lc[i].y * PP + pc[i].y) * TPB + tid], p[i].y);
        atomicAdd(&sb[(60 + lc[i].y) * TPB + tid], 1.0f);
        atomicAdd(&sb[(lc[i].z * PP + pc[i].z) * TPB + tid], p[i].z);
        atomicAdd(&sb[(60 + lc[i].z) * TPB + tid], 1.0f);
        atomicAdd(&sb[(lc[i].w * PP + pc[i].w) * TPB + tid], p[i].w);
        atomicAdd(&sb[(60 + lc[i].w) * TPB + tid], 1.0f);
    }
    __syncthreads();

    float* wout = ws + ((size_t)img * BX + blockIdx.x) * BINS;

    // Block reduction, bins 0..63: thread t -> (bin = t>>2, quarter = t&3).
    // Rotated float4 reads break the same-bank stride.
    {
        const int b = tid >> 2, q = tid & 3;
        const float* col = sb + b * TPB + 64 * q;
        float s = 0.0f;
#pragma unroll
        for (int i = 0; i < 16; ++i) {
            const int ii = ((i + tid) & 15) * 4;
            const float4 t4 = *(const float4*)(col + ii);
            s += t4.x + t4.y + t4.z + t4.w;
        }
        s += __shfl_down(s, 1, 64);
        s += __shfl_down(s, 2, 64);
        if (q == 0) wout[b] = s;   // non-atomic partial store
    }
    // Bins 64, 65: threads 0..7 (one 4-thread group per bin).
    if (tid < 8) {
        const int b = 64 + (tid >> 2), q = tid & 3;
        const float* col = sb + b * TPB + 64 * q;
        float s = 0.0f;
#pragma unroll
        for (int i = 0; i < 16; ++i) {
            const float4 t4 = *(const float4*)(col + i * 4);
            s += t4.x + t4.y + t4.z + t4.w;
        }
        s += __shfl_down(s, 1, 64);
        s += __shfl_down(s, 2, 64);
        if (q == 0) wout[b] = s;
    }
}

__global__ __launch_bounds__(320) void finalize_kernel(
    const float* __restrict__ ws, float* __restrict__ out)
{
    __shared__ float red[NIMG * BINS];
    __shared__ float contrib[NIMG];
    const int t = threadIdx.x;

    if (t < NIMG * BINS) {
        const int img = t / BINS, b = t % BINS;
        const float* base = ws + (size_t)img * BX * BINS + b;
        float s = 0.0f;
#pragma unroll 8
        for (int bx = 0; bx < BX; ++bx) s += base[bx * BINS];
        red[t] = s;
    }
    __syncthreads();

    if (t < NIMG) {
        const float* b = red + t * BINS;
        float inter[LL][PP];
        float pred_area[PP];
        float label_area[LL];
        for (int p = 0; p < PP; ++p) pred_area[p] = 0.0f;
        for (int l = 0; l < LL; ++l) {
            label_area[l] = b[60 + l];
            for (int p = 0; p < PP; ++p) {
                inter[l][p] = b[l * PP + p];
                pred_area[p] += inter[l][p];
            }
        }
        float ious[LL][PP];
        for (int l = 1; l < LL; ++l) {
            for (int p = 1; p < PP; ++p) {
                float in = inter[l][p];
                float un = label_area[l] + pred_area[p] - in;
                float iou;
                if (in == 0.0f)      iou = 0.0f;
                else if (un == 0.0f) iou = 1.0f;
                else                 iou = in / un;
                ious[l][p] = iou;
            }
        }
        float pair_conn_sum = 0.0f;
        for (int l = 1; l < LL; ++l) {
            float pc = 0.0f; int pn = 0;
            for (int p = 1; p < PP; ++p) {
                pc += ious[l][p];
                pn += (ious[l][p] != 0.0f) ? 1 : 0;
            }
            if (pn > 0) pair_conn_sum += pc / (float)pn;
        }
        int lone = 0;
        for (int p = 1; p < PP; ++p) {
            float cs = 0.0f;
            for (int l = 1; l < LL; ++l) cs += ious[l][p];
            lone += (cs == 0.0f) ? 1 : 0;
        }
        contrib[t] = 1.0f - pair_conn_sum / (5.0f + (float)lone);
    }
    __syncthreads();

    if (t == 0)
        out[0] = (contrib[0] + contrib[1] + contrib[2] + contrib[3]) * 0.25f;
}

extern "C" void kernel_launch(void* const* d_in, const int* in_sizes, int n_in,
                              void* d_out, int out_size, void* d_ws, size_t ws_size,
                              hipStream_t stream) {
    const float* pred  = (const float*)d_in[0];
    const int*   pconn = (const int*)d_in[1];
    const int*   lconn = (const int*)d_in[2];
    float* out = (float*)d_out;
    float* ws  = (float*)d_ws;

    dim3 grid(BX, NIMG);
    accum_kernel<<<grid, TPB, 0, stream>>>(pred, pconn, lconn, ws);

    finalize_kernel<<<1, 320, 0, stream>>>(ws, out);
}

// Round 4
// 109.625 us; speedup vs baseline: 1.1805x; 1.1805x over previous
//
#include <hip/hip_runtime.h>

#define PP 10
#define LL 6
#define NIMG 4
#define HW (1024*1024)
#define BINS 66          // ws layout: 60 inter bins (l*10+p) + 6 count bins
#define NB 60            // LDS-privatized inter bins only
#define BX 512           // blocks per image
#define TPB 128
#define ITERS 4          // HW/4 / (BX*TPB) = 4, exact

// ws: partial[img][bx][b] = ws[(img*BX+bx)*BINS + b], non-atomic stores.

__global__ __launch_bounds__(TPB, 2) void accum_kernel(
    const float* __restrict__ pred,
    const int*   __restrict__ pconn,
    const int*   __restrict__ lconn,
    float*       __restrict__ ws)
{
    // Per-thread privatized inter bins: sb[b*128 + tid]; bank = tid%32 ->
    // 2 lanes/bank (free, m136). 30.7 KB -> 5 blocks/CU = 10 waves/CU.
    __shared__ float sb[NB * TPB];
    __shared__ float scnt[2][8];

    const int tid = threadIdx.x;
    const int img = blockIdx.y;
    const size_t base = (size_t)img * HW;

    {   // zero LDS: 1920 float4 / 128 threads = 15 each
        float4* sb4 = (float4*)sb;
        for (int i = tid; i < NB * TPB / 4; i += TPB)
            sb4[i] = make_float4(0.f, 0.f, 0.f, 0.f);
    }
    __syncthreads();

    const float4* __restrict__ p4  = (const float4*)(pred  + base);
    const int4*   __restrict__ pc4 = (const int4*)(pconn + base);
    const int4*   __restrict__ lc4 = (const int4*)(lconn + base);

    const int v0 = blockIdx.x * TPB + tid;
    const int stride = BX * TPB;   // 65536 vec4s

    // Hoist ALL 12 loads (48 VGPRs) -> one full-latency wait per wave.
    float4 p[ITERS]; int4 pc[ITERS], lc[ITERS];
#pragma unroll
    for (int i = 0; i < ITERS; ++i) {
        const int v = v0 + i * stride;
        p[i]  = p4[v];
        pc[i] = pc4[v];
        lc[i] = lc4[v];
    }

    // Label counts in registers (VALU is idle): no LDS traffic for them.
    float cnt[LL];
#pragma unroll
    for (int l = 0; l < LL; ++l) cnt[l] = 0.0f;

#pragma unroll
    for (int i = 0; i < ITERS; ++i) {
#pragma unroll
        for (int l = 0; l < LL; ++l)
            cnt[l] += (float)((lc[i].x == l) + (lc[i].y == l)
                            + (lc[i].z == l) + (lc[i].w == l));
        // Private += : plain ds_read/ds_write, no atomics (R3 lesson).
        sb[(lc[i].x * PP + pc[i].x) * TPB + tid] += p[i].x;
        sb[(lc[i].y * PP + pc[i].y) * TPB + tid] += p[i].y;
        sb[(lc[i].z * PP + pc[i].z) * TPB + tid] += p[i].z;
        sb[(lc[i].w * PP + pc[i].w) * TPB + tid] += p[i].w;
    }
    __syncthreads();

    float* wout = ws + ((size_t)img * BX + blockIdx.x) * BINS;

    // Count reduce: full-wave shuffle, then cross-wave via tiny LDS.
#pragma unroll
    for (int l = 0; l < LL; ++l) {
        float s = cnt[l];
        s += __shfl_down(s, 32, 64); s += __shfl_down(s, 16, 64);
        s += __shfl_down(s,  8, 64); s += __shfl_down(s,  4, 64);
        s += __shfl_down(s,  2, 64); s += __shfl_down(s,  1, 64);
        if ((tid & 63) == 0) scnt[tid >> 6][l] = s;
    }

    // Bin reduce: thread pair (2b, 2b+1) sums the 128 columns of bin b.
    {
        const int b = tid >> 1, h = tid & 1;
        if (b < NB) {
            const float* col = sb + b * TPB + 64 * h;
            float s = 0.0f;
#pragma unroll
            for (int i = 0; i < 16; ++i) {
                const int ii = ((i + tid) & 15) * 4;   // rotation vs banks
                const float4 t4 = *(const float4*)(col + ii);
                s += t4.x + t4.y + t4.z + t4.w;
            }
            s += __shfl_down(s, 1, 64);
            if (h == 0) wout[b] = s;
        }
    }
    __syncthreads();
    if (tid < LL) wout[NB + tid] = scnt[0][tid] + scnt[1][tid];
}

__global__ __launch_bounds__(1024) void finalize_kernel(
    const float* __restrict__ ws, float* __restrict__ out)
{
    __shared__ float part[4][NIMG * BINS];   // [sub][img*66+b]
    __shared__ float red[NIMG * BINS];
    __shared__ float contrib[NIMG];
    const int t = threadIdx.x;

    // 1056 tasks: (img,bin) x 4 sub-chunks of 128 bx each.
    for (int T = t; T < 4 * NIMG * BINS; T += 1024) {
        const int ib = T >> 2, sub = T & 3;
        const int img = ib / BINS, b = ib % BINS;
        const float* basep = ws + ((size_t)img * BX + sub) * BINS + b;
        float s = 0.0f;
#pragma unroll 8
        for (int j = 0; j < BX / 4; ++j) s += basep[(size_t)j * 4 * BINS];
        part[sub][ib] = s;
    }
    __syncthreads();

    if (t < NIMG * BINS)
        red[t] = part[0][t] + part[1][t] + part[2][t] + part[3][t];
    __syncthreads();

    if (t < NIMG) {
        const float* b = red + t * BINS;
        float inter[LL][PP], pred_area[PP], label_area[LL];
        for (int p = 0; p < PP; ++p) pred_area[p] = 0.0f;
        for (int l = 0; l < LL; ++l) {
            label_area[l] = b[NB + l];
            for (int p = 0; p < PP; ++p) {
                inter[l][p] = b[l * PP + p];
                pred_area[p] += inter[l][p];
            }
        }
        float ious[LL][PP];
        for (int l = 1; l < LL; ++l) {
            for (int p = 1; p < PP; ++p) {
                float in = inter[l][p];
                float un = label_area[l] + pred_area[p] - in;
                float iou;
                if (in == 0.0f)      iou = 0.0f;
                else if (un == 0.0f) iou = 1.0f;
                else                 iou = in / un;
                ious[l][p] = iou;
            }
        }
        float pair_conn_sum = 0.0f;
        for (int l = 1; l < LL; ++l) {
            float pc = 0.0f; int pn = 0;
            for (int p = 1; p < PP; ++p) {
                pc += ious[l][p];
                pn += (ious[l][p] != 0.0f) ? 1 : 0;
            }
            if (pn > 0) pair_conn_sum += pc / (float)pn;
        }
        int lone = 0;
        for (int p = 1; p < PP; ++p) {
            float cs = 0.0f;
            for (int l = 1; l < LL; ++l) cs += ious[l][p];
            lone += (cs == 0.0f) ? 1 : 0;
        }
        contrib[t] = 1.0f - pair_conn_sum / (5.0f + (float)lone);
    }
    __syncthreads();
    if (t == 0)
        out[0] = (contrib[0] + contrib[1] + contrib[2] + contrib[3]) * 0.25f;
}

extern "C" void kernel_launch(void* const* d_in, const int* in_sizes, int n_in,
                              void* d_out, int out_size, void* d_ws, size_t ws_size,
                              hipStream_t stream) {
    const float* pred  = (const float*)d_in[0];
    const int*   pconn = (const int*)d_in[1];
    const int*   lconn = (const int*)d_in[2];
    float* out = (float*)d_out;
    float* ws  = (float*)d_ws;

    dim3 grid(BX, NIMG);
    accum_kernel<<<grid, TPB, 0, stream>>>(pred, pconn, lconn, ws);

    finalize_kernel<<<1, 1024, 0, stream>>>(ws, out);
}